// Round 7
// baseline (290.401 us; speedup 1.0000x reference)
//
#include <hip/hip_runtime.h>
#include <math.h>

#define QN 21760
#define MTOT 43520   // = 680 * 64

typedef __attribute__((ext_vector_type(8))) short bf16x8;
typedef __attribute__((ext_vector_type(4))) float f32x4;

__device__ inline ushort f2bf(float f) {
  union { float f; uint u; } v; v.f = f;
  return (ushort)((v.u + 0x7FFFu + ((v.u >> 16) & 1u)) >> 16);
}
__device__ inline uint pk2(float lo, float hi) { return (uint)f2bf(lo) | ((uint)f2bf(hi) << 16); }

__device__ inline void g2l(const ushort* g, ushort* l) {
  __builtin_amdgcn_global_load_lds(
      (const __attribute__((address_space(1))) void*)g,
      (__attribute__((address_space(3))) void*)l, 16, 0, 0);
}

// ---------------- weight prep ----------------
__global__ __launch_bounds__(256) void prep_weights(
    const float* __restrict__ Wv, const float* __restrict__ Wout,
    const float* __restrict__ Woff, const float* __restrict__ Wattn,
    const float* __restrict__ boff, const float* __restrict__ battn,
    ushort* __restrict__ wv_t, ushort* __restrict__ wout_t,
    ushort* __restrict__ wol_t, float* __restrict__ biasf) {
  int bidx = blockIdx.x, t = threadIdx.x;
  if (bidx < 256) {
    int idx = bidx * 256 + t; int n = idx >> 8, k = idx & 255;
    wv_t[idx] = f2bf(Wv[(size_t)k * 256 + n]);
  } else if (bidx < 512) {
    int idx = (bidx - 256) * 256 + t; int n = idx >> 8, k = idx & 255;
    wout_t[idx] = f2bf(Wout[(size_t)k * 256 + n]);
  } else {
    int idx = (bidx - 512) * 256 + t; int n = idx >> 8, k = idx & 255;
    float v = (n < 256) ? Woff[(size_t)k * 256 + n] : Wattn[(size_t)k * 128 + (n - 256)];
    wol_t[idx] = f2bf(v);
    if (idx < 384) biasf[idx] = (idx < 256) ? boff[idx] : battn[idx - 256];
  }
}

// ---- XOR-swizzled LDS slab: 64 rows x 32 ushort; 16B chunk c of row r at
// physical chunk c ^ ((r>>1)&3). Frag ds_read_b128 conflict-free. ----

// ---------------- A-resident input GEMM (val + offlog) ----------------
// grid (680, 2). by=0: A=value (f32), 2 panels of Wv -> val fp16 head-split.
//                by=1: A=query (f32), 3 panels of Wol -> offlog f32 (M,384).
// A-tile 64x256 staged ONCE (cast fused); B slabs double-buffered via g2l.
__global__ __launch_bounds__(256) void gemm_in2(
    const float* __restrict__ value, const float* __restrict__ query,
    const ushort* __restrict__ Wv, const ushort* __restrict__ Wol,
    const float* __restrict__ bv, const float* __restrict__ bol,
    ushort* __restrict__ val_out, float* __restrict__ offlog) {
  __shared__ ushort Ares[8 * 2048];   // 8 slabs of 64x32 = 32 KB
  __shared__ ushort Bs[2][4096];      // 128x32 slab dbuf = 16 KB
  const int t = threadIdx.x, wave = t >> 6, lane = t & 63;
  const int bm = blockIdx.x * 64;
  const bool isVal = (blockIdx.y == 0);
  const float* A    = isVal ? value : query;
  const ushort* Bt0 = isVal ? Wv : Wol;
  const int np = isVal ? 2 : 3;
  const int l15 = lane & 15, l4 = lane >> 4;
  const int pc = l4 ^ ((l15 >> 1) & 3);
  const int wm = (wave >> 1) * 32, wn = (wave & 1) * 64;

  // ---- stage A: 64x256 f32 -> bf16, swizzled slabs ----
  const float4* Af4 = (const float4*)(A + (size_t)bm * 256);
#pragma unroll
  for (int i = 0; i < 16; ++i) {
    int f = i * 256 + t;                 // float4 index in 64x64 grid
    int row = f >> 6, col4 = f & 63;
    float4 v = Af4[f];
    int k = col4 >> 3, part = col4 & 7;
    int pc16 = (part >> 1) ^ ((row >> 1) & 3);
    ushort4 hv = { f2bf(v.x), f2bf(v.y), f2bf(v.z), f2bf(v.w) };
    *(ushort4*)&Ares[k * 2048 + row * 32 + pc16 * 8 + (part & 1) * 4] = hv;
  }

  // B staging: wave w covers rows [32w, 32w+32) of the 128x32 slab
  const int srow = lane >> 2, sch = (lane & 3) ^ ((lane >> 3) & 3);
  const int brow = 32 * wave + srow;
  ushort* lb[2] = { &Bs[0][(32 * wave) * 32], &Bs[1][(32 * wave) * 32] };
  {
    const ushort* Bg = Bt0 + (size_t)brow * 256 + sch * 8;   // panel 0, k 0
    g2l(Bg, lb[0]); g2l(Bg + 16 * 256, lb[0] + 16 * 32);
  }

  f32x4 acc[2][4];
#pragma unroll
  for (int i = 0; i < 2; ++i)
#pragma unroll
    for (int j = 0; j < 4; ++j) acc[i][j] = (f32x4){0.f, 0.f, 0.f, 0.f};

  const int total = np * 8;
  for (int j = 0; j < total; ++j) {
    __syncthreads();
    const int cur = j & 1, nxt = cur ^ 1;
    if (j + 1 < total) {
      int jn = j + 1, pn = jn >> 3, kn = jn & 7;
      const ushort* Bg = Bt0 + (size_t)(pn * 128 + brow) * 256 + kn * 32 + sch * 8;
      g2l(Bg, lb[nxt]); g2l(Bg + 16 * 256, lb[nxt] + 16 * 32);
    }
    const int k = j & 7;
    bf16x8 af[2], bfr[4];
#pragma unroll
    for (int mi = 0; mi < 2; ++mi)
      af[mi] = *(const bf16x8*)&Ares[k * 2048 + (wm + mi * 16 + l15) * 32 + pc * 8];
#pragma unroll
    for (int ni = 0; ni < 4; ++ni)
      bfr[ni] = *(const bf16x8*)&Bs[cur][(wn + ni * 16 + l15) * 32 + pc * 8];
#pragma unroll
    for (int mi = 0; mi < 2; ++mi)
#pragma unroll
      for (int ni = 0; ni < 4; ++ni)
        acc[mi][ni] = __builtin_amdgcn_mfma_f32_16x16x32_bf16(af[mi], bfr[ni], acc[mi][ni], 0, 0, 0);

    if (k == 7) {
      const int p = j >> 3;
      if (isVal) {
        _Float16* vo = (_Float16*)val_out;
#pragma unroll
        for (int mi = 0; mi < 2; ++mi)
#pragma unroll
          for (int ni = 0; ni < 4; ++ni) {
            int col = p * 128 + wn + ni * 16 + l15;
            float bb = bv[col];
            int hh = col >> 5, c = col & 31;
#pragma unroll
            for (int r = 0; r < 4; ++r) {
              int row = bm + wm + mi * 16 + l4 * 4 + r;
              int b = (row >= QN) ? 1 : 0;
              int vpos = row - b * QN;
              vo[((size_t)(b * 8 + hh) * QN + vpos) * 32 + c] = (_Float16)(acc[mi][ni][r] + bb);
            }
          }
      } else {
#pragma unroll
        for (int mi = 0; mi < 2; ++mi)
#pragma unroll
          for (int ni = 0; ni < 4; ++ni) {
            int col = p * 128 + wn + ni * 16 + l15;
            float bb = bol[col];
#pragma unroll
            for (int r = 0; r < 4; ++r) {
              int row = bm + wm + mi * 16 + l4 * 4 + r;
              offlog[(size_t)row * 384 + col] = acc[mi][ni][r] + bb;
            }
          }
      }
#pragma unroll
      for (int i = 0; i < 2; ++i)
#pragma unroll
        for (int jj = 0; jj < 4; ++jj) acc[i][jj] = (f32x4){0.f, 0.f, 0.f, 0.f};
    }
  }
}

// ---------------- A-resident output GEMM ----------------
// grid (680). A = interm bf16 (M,256) staged once via g2l; 2 panels of Wout.
__global__ __launch_bounds__(256) void gemm_out2(
    const ushort* __restrict__ A, const ushort* __restrict__ Bt,
    const float* __restrict__ bias, float* __restrict__ C) {
  __shared__ ushort Ares[8 * 2048];
  __shared__ ushort Bs[2][4096];
  const int t = threadIdx.x, wave = t >> 6, lane = t & 63;
  const int bm = blockIdx.x * 64;
  const int l15 = lane & 15, l4 = lane >> 4;
  const int pc = l4 ^ ((l15 >> 1) & 3);
  const int wm = (wave >> 1) * 32, wn = (wave & 1) * 64;
  const int srow = lane >> 2, sch = (lane & 3) ^ ((lane >> 3) & 3);

  // ---- stage A via g2l: wave w covers rows [16w, 16w+16) across 8 slabs ----
  const int rowbase = 16 * wave;
  const ushort* Ag = A + (size_t)(bm + rowbase + srow) * 256 + sch * 8;
#pragma unroll
  for (int k = 0; k < 8; ++k)
    g2l(Ag + k * 32, &Ares[k * 2048 + rowbase * 32]);

  const int brow = 32 * wave + srow;
  ushort* lb[2] = { &Bs[0][(32 * wave) * 32], &Bs[1][(32 * wave) * 32] };
  {
    const ushort* Bg = Bt + (size_t)brow * 256 + sch * 8;
    g2l(Bg, lb[0]); g2l(Bg + 16 * 256, lb[0] + 16 * 32);
  }

  f32x4 acc[2][4];
#pragma unroll
  for (int i = 0; i < 2; ++i)
#pragma unroll
    for (int j = 0; j < 4; ++j) acc[i][j] = (f32x4){0.f, 0.f, 0.f, 0.f};

  for (int j = 0; j < 16; ++j) {
    __syncthreads();
    const int cur = j & 1, nxt = cur ^ 1;
    if (j + 1 < 16) {
      int jn = j + 1, pn = jn >> 3, kn = jn & 7;
      const ushort* Bg = Bt + (size_t)(pn * 128 + brow) * 256 + kn * 32 + sch * 8;
      g2l(Bg, lb[nxt]); g2l(Bg + 16 * 256, lb[nxt] + 16 * 32);
    }
    const int k = j & 7;
    bf16x8 af[2], bfr[4];
#pragma unroll
    for (int mi = 0; mi < 2; ++mi)
      af[mi] = *(const bf16x8*)&Ares[k * 2048 + (wm + mi * 16 + l15) * 32 + pc * 8];
#pragma unroll
    for (int ni = 0; ni < 4; ++ni)
      bfr[ni] = *(const bf16x8*)&Bs[cur][(wn + ni * 16 + l15) * 32 + pc * 8];
#pragma unroll
    for (int mi = 0; mi < 2; ++mi)
#pragma unroll
      for (int ni = 0; ni < 4; ++ni)
        acc[mi][ni] = __builtin_amdgcn_mfma_f32_16x16x32_bf16(af[mi], bfr[ni], acc[mi][ni], 0, 0, 0);

    if (k == 7) {
      const int p = j >> 3;
#pragma unroll
      for (int mi = 0; mi < 2; ++mi)
#pragma unroll
        for (int ni = 0; ni < 4; ++ni) {
          int col = p * 128 + wn + ni * 16 + l15;
          float bb = bias[col];
#pragma unroll
          for (int r = 0; r < 4; ++r) {
            int row = bm + wm + mi * 16 + l4 * 4 + r;
            C[(size_t)row * 256 + col] = acc[mi][ni][r] + bb;
          }
        }
#pragma unroll
      for (int i = 0; i < 2; ++i)
#pragma unroll
        for (int jj = 0; jj < 4; ++jj) acc[i][jj] = (f32x4){0.f, 0.f, 0.f, 0.f};
    }
  }
}

// ---------------- deformable sampling (unchanged from round 6) ----------------
__device__ inline void fmah(float* a, uint4 u, float wv) {
  union { uint4 u; _Float16 h[8]; } c; c.u = u;
#pragma unroll
  for (int i = 0; i < 8; ++i) a[i] = fmaf((float)c.h[i], wv, a[i]);
}

__global__ __launch_bounds__(256) void msda_sample(
    const ushort* __restrict__ val, const float* __restrict__ offlog,
    const float* __restrict__ ref, ushort* __restrict__ interm) {
  const int lsz[4]    = {128, 64, 32, 16};
  const int lstart[4] = {0, 16384, 20480, 21504};

  int h   = blockIdx.x & 7;
  int z   = blockIdx.x >> 3;
  int sub = threadIdx.x & 3;
  int bq  = z * 64 + (threadIdx.x >> 2);
  int b   = (bq >= QN) ? 1 : 0;

  const float* lgp = offlog + (size_t)bq * 384 + 256 + h * 16;
  float w[16];
  {
    float4 a0 = *(const float4*)(lgp);
    float4 a1 = *(const float4*)(lgp + 4);
    float4 a2 = *(const float4*)(lgp + 8);
    float4 a3 = *(const float4*)(lgp + 12);
    w[0]=a0.x; w[1]=a0.y; w[2]=a0.z; w[3]=a0.w;
    w[4]=a1.x; w[5]=a1.y; w[6]=a1.z; w[7]=a1.w;
    w[8]=a2.x; w[9]=a2.y; w[10]=a2.z; w[11]=a2.w;
    w[12]=a3.x; w[13]=a3.y; w[14]=a3.z; w[15]=a3.w;
  }
  float m = -1e30f;
#pragma unroll
  for (int s = 0; s < 16; ++s) m = fmaxf(m, w[s]);
  float sum = 0.f;
#pragma unroll
  for (int s = 0; s < 16; ++s) { w[s] = __expf(w[s] - m); sum += w[s]; }
  float inv = 1.f / sum;

  const float* offp = offlog + (size_t)bq * 384 + h * 32;
  const float* refp = ref + (size_t)bq * 8;
  const ushort* vb  = val + ((size_t)(b * 8 + h) * QN) * 32 + sub * 8;

  float acc[8];
#pragma unroll
  for (int i = 0; i < 8; ++i) acc[i] = 0.f;

#pragma unroll
  for (int l = 0; l < 4; ++l) {
    float4 o0 = *(const float4*)(offp + l * 8);
    float4 o1 = *(const float4*)(offp + l * 8 + 4);
    float ox[4] = { o0.x, o0.z, o1.x, o1.z };
    float oy[4] = { o0.y, o0.w, o1.y, o1.w };
    const int   W = lsz[l];
    const float fW = (float)W;
    const int   base = lstart[l];
    const float rx = refp[l * 2 + 0], ry = refp[l * 2 + 1];
#pragma unroll
    for (int p = 0; p < 4; ++p) {
      float x = rx * fW + ox[p] - 0.5f;
      float y = ry * fW + oy[p] - 0.5f;
      float x0f = floorf(x), y0f = floorf(y);
      int   x0 = (int)x0f,   y0 = (int)y0f;
      float fx = x - x0f,    fy = y - y0f;
      float a = w[l * 4 + p] * inv;
      const ushort* r0 = vb + (size_t)(base + y0 * W + x0) * 32;
      const ushort* r1 = r0 + (size_t)W * 32;

      if (x0 >= 0 && y0 >= 0 && x0 + 1 < W && y0 + 1 < W) {
        uint4 u00 = *(const uint4*)r0;
        uint4 u10 = *(const uint4*)(r0 + 32);
        uint4 u01 = *(const uint4*)r1;
        uint4 u11 = *(const uint4*)(r1 + 32);
        float w00 = (1.f - fx) * (1.f - fy) * a;
        float w10 = fx * (1.f - fy) * a;
        float w01 = (1.f - fx) * fy * a;
        float w11 = fx * fy * a;
        fmah(acc, u00, w00); fmah(acc, u10, w10);
        fmah(acc, u01, w01); fmah(acc, u11, w11);
      } else {
        float wx0 = (x0 >= 0 && x0 < W) ? (1.f - fx) : 0.f;
        float wx1 = (x0 + 1 >= 0 && x0 + 1 < W) ? fx : 0.f;
        float wy0 = (y0 >= 0 && y0 < W) ? (1.f - fy) : 0.f;
        float wy1 = (y0 + 1 >= 0 && y0 + 1 < W) ? fy : 0.f;
        float w00 = wx0 * wy0 * a, w10 = wx1 * wy0 * a;
        float w01 = wx0 * wy1 * a, w11 = wx1 * wy1 * a;
        if (w00 != 0.f) { uint4 u = *(const uint4*)r0;        fmah(acc, u, w00); }
        if (w10 != 0.f) { uint4 u = *(const uint4*)(r0 + 32); fmah(acc, u, w10); }
        if (w01 != 0.f) { uint4 u = *(const uint4*)r1;        fmah(acc, u, w01); }
        if (w11 != 0.f) { uint4 u = *(const uint4*)(r1 + 32); fmah(acc, u, w11); }
      }
    }
  }

  uint4 o;
  o.x = pk2(acc[0], acc[1]); o.y = pk2(acc[2], acc[3]);
  o.z = pk2(acc[4], acc[5]); o.w = pk2(acc[6], acc[7]);
  *(uint4*)(interm + (size_t)bq * 256 + h * 32 + sub * 8) = o;
}

extern "C" void kernel_launch(void* const* d_in, const int* in_sizes, int n_in,
                              void* d_out, int out_size, void* d_ws, size_t ws_size,
                              hipStream_t stream) {
  const float* query = (const float*)d_in[0];
  const float* value = (const float*)d_in[1];
  const float* ref   = (const float*)d_in[2];
  const float* W_off  = (const float*)d_in[4];
  const float* b_off  = (const float*)d_in[5];
  const float* W_attn = (const float*)d_in[6];
  const float* b_attn = (const float*)d_in[7];
  const float* W_v    = (const float*)d_in[8];
  const float* b_v    = (const float*)d_in[9];
  const float* W_out  = (const float*)d_in[10];
  const float* b_out  = (const float*)d_in[11];
  float* out = (float*)d_out;

  // ---- workspace (byte offsets, 256-aligned) ----
  char* wsb = (char*)d_ws;
  ushort* ws_wv     = (ushort*)(wsb + 0);          // 131072 B
  ushort* ws_wol    = (ushort*)(wsb + 131072);     // 196608 B
  ushort* ws_wout   = (ushort*)(wsb + 327680);     // 131072 B
  float*  ws_biasf  = (float*)(wsb + 458752);      // 4096 B
  ushort* ws_val    = (ushort*)(wsb + 462848);     // 22282240 B fp16 head-split
  ushort* ws_interm = (ushort*)(wsb + 22745088);   // 22282240 B bf16 (M,256)
  float*  ws_offlog = (float*)(wsb + 45027328);    // 66846720 B f32 (M,384)
  size_t need = (size_t)45027328 + 66846720;       // ~112 MB
  if (ws_size < need) return;

  dim3 blk(256);
  prep_weights<<<dim3(896), blk, 0, stream>>>(W_v, W_out, W_off, W_attn, b_off, b_attn,
                                              ws_wv, ws_wout, ws_wol, ws_biasf);
  gemm_in2<<<dim3(680, 2), blk, 0, stream>>>(value, query, ws_wv, ws_wol, b_v, ws_biasf,
                                             ws_val, ws_offlog);
  msda_sample<<<dim3(5440), blk, 0, stream>>>(ws_val, ws_offlog, ref, ws_interm);
  gemm_out2<<<dim3(680), blk, 0, stream>>>(ws_interm, ws_wout, b_out, out);
}